// Round 6
// baseline (543.557 us; speedup 1.0000x reference)
//
#include <hip/hip_runtime.h>

// SSIM (win=7, valid) fused single-pass kernel for (32,3,512,512) fp32 inputs.
// 96 images of 512x512 -> mean over 96x506x506 S map.
//
// R6: fix latency starvation with TLP. R5 showed inputs are L3-resident on
// replay (FETCH ~0) yet dur is flat ~110 us across all structures with every
// throughput pipe at <25% -> pure memory-latency starvation at 2.16 waves/SIMD.
// This round: RSTRIP=8 -> 64 strips x 96 images = 6144 single-wave blocks
// = 6 waves/SIMD demand; __launch_bounds__(64,6) caps VGPRs at 85 so all 6
// are resident. Per-wave structure unchanged from R4 (8 cols/lane, register
// V-slide, shuffle halo, folded constants, rcp). Last strip overlaps and
// gates its first 6 rows instead of a variable loop bound. Per-image atomic
// slots (96) to avoid single-cacheline atomic serialization.

namespace {
constexpr int W      = 512;
constexpr int HH     = 512;
constexpr int NIMG   = 96;
constexpr int OW     = 506;
constexpr int RSTRIP = 8;
constexpr int NSTRIP = 64;   // 63 full strips + overlapped tail strip
// S = (2 ux uy + C1)(2 vxy + C2) / ((ux^2+uy^2+C1)(vx+vy+C2)); with U = 49*u
// window sums, every term carries 1/2401 which cancels in the ratio:
constexpr float D1      = 0.2401f;                  // C1 * 49^2
constexpr float D2      = 2.1609f;                  // C2 * 49^2
constexpr float COVN    = 49.0f / 48.0f;            // NP/(NP-1)
constexpr float COV2    = 2.0f * COVN;
constexpr float K49COV  = 49.0f * COVN;
constexpr float K49COV2 = 2.0f * 49.0f * COVN;
constexpr double NPIX   = 96.0 * 506.0 * 506.0;     // 24,579,456
}

__global__ __launch_bounds__(64, 6) void ssim_main(const float* __restrict__ X,
                                                   const float* __restrict__ Y,
                                                   double* __restrict__ acc)
{
    const int lane = threadIdx.x;              // 0..63 (one wave per block)
    const int img  = blockIdx.y;
    int r0     = blockIdx.x * RSTRIP;          // first output row of strip
    int jstart = 0;                            // rows < jstart already owned by prev strip
    if (r0 > OW - RSTRIP) {                    // tail strip: overlap backwards
        jstart = r0 - (OW - RSTRIP);
        r0     = OW - RSTRIP;
    }
    const int c0 = lane * 8;                   // this lane's first column

    const float* xb = X + (size_t)img * (W * HH) + c0;
    const float* yb = Y + (size_t)img * (W * HH) + c0;

    // vertical running sums over the 7-row window, per own column 0..7:
    // V[0]=sum x, V[1]=sum y, V[2]=sum x^2, V[3]=sum y^2, V[4]=sum x*y
    float V[5][8];
#pragma unroll
    for (int q = 0; q < 5; q++)
#pragma unroll
        for (int i = 0; i < 8; i++) V[q][i] = 0.0f;

    float xr[8], yr[8], xo[8], yo[8];

    auto load_row = [&](int r, float (&dx)[8], float (&dy)[8]) {
        const float* px = xb + (size_t)r * W;
        const float* py = yb + (size_t)r * W;
        float4 a = *(const float4*)px;
        float4 b = *(const float4*)(px + 4);
        dx[0] = a.x; dx[1] = a.y; dx[2] = a.z; dx[3] = a.w;
        dx[4] = b.x; dx[5] = b.y; dx[6] = b.z; dx[7] = b.w;
        float4 e = *(const float4*)py;
        float4 f = *(const float4*)(py + 4);
        dy[0] = e.x; dy[1] = e.y; dy[2] = e.z; dy[3] = e.w;
        dy[4] = f.x; dy[5] = f.y; dy[6] = f.z; dy[7] = f.w;
    };

    // warm-up: rows r0 .. r0+5
#pragma unroll
    for (int k = 0; k < 6; k++) {
        load_row(r0 + k, xr, yr);
#pragma unroll
        for (int i = 0; i < 8; i++) {
            V[0][i] += xr[i];
            V[1][i] += yr[i];
            V[2][i] = fmaf(xr[i], xr[i], V[2][i]);
            V[3][i] = fmaf(yr[i], yr[i], V[3][i]);
            V[4][i] = fmaf(xr[i], yr[i], V[4][i]);
        }
    }
    // first bottom row of the window
    load_row(r0 + 6, xr, yr);

    float sacc = 0.0f;

#pragma unroll
    for (int j = 0; j < RSTRIP; j++) {
        // add bottom row (r0 + j + 6), already in xr/yr
#pragma unroll
        for (int i = 0; i < 8; i++) {
            V[0][i] += xr[i];
            V[1][i] += yr[i];
            V[2][i] = fmaf(xr[i], xr[i], V[2][i]);
            V[3][i] = fmaf(yr[i], yr[i], V[3][i]);
            V[4][i] = fmaf(xr[i], yr[i], V[4][i]);
        }

        // prefetch: top row (subtract at iter end) and next bottom row
        // (consumed next iter) — xr/yr were just consumed, safe to overwrite.
        load_row(r0 + j, xo, yo);
        int rn = r0 + j + 7; if (rn > HH - 1) rn = HH - 1;  // clamped; dead on last iter
        load_row(rn, xr, yr);

        // halo: V cols 8..13 = lane+1's cols 0..5 (lane 63's valid outputs
        // never touch halo; its garbage feeds only masked pixels)
        float Vh[5][6];
#pragma unroll
        for (int q = 0; q < 5; q++)
#pragma unroll
            for (int i = 0; i < 6; i++) Vh[q][i] = __shfl_down(V[q][i], 1);

        // horizontal window init (cols 0..6), then slide across 8 outputs
        float H[5];
#pragma unroll
        for (int q = 0; q < 5; q++)
            H[q] = ((V[q][0] + V[q][1]) + (V[q][2] + V[q][3])) +
                   ((V[q][4] + V[q][5]) + V[q][6]);

        const bool rowok = (j >= jstart);   // tail-strip overlap gating
#pragma unroll
        for (int i = 0; i < 8; i++) {
            float U0 = H[0], U1 = H[1], U2 = H[2], U3 = H[3], U4 = H[4];
            float A    = U0 * U1;
            float q01  = fmaf(U0, U0, U1 * U1);
            float num1 = fmaf(2.0f, A, D1);
            float den1 = q01 + D1;
            float num2 = fmaf(K49COV2, U4, fmaf(-COV2, A, D2));
            float s23  = U2 + U3;
            float den2 = fmaf(K49COV, s23, fmaf(-COVN, q01, D2));
            float S = (num1 * num2) * __builtin_amdgcn_rcpf(den1 * den2);
            sacc += (rowok && (c0 + i < OW)) ? S : 0.0f;
            if (i < 7) {
                // slide window i..i+6 -> i+1..i+7: add col i+7, drop col i
#pragma unroll
                for (int q = 0; q < 5; q++) {
                    float addv = (i == 0) ? V[q][7] : Vh[q][i - 1];
                    H[q] += addv - V[q][i];
                }
            }
        }

        // subtract top row (r0 + j)
#pragma unroll
        for (int i = 0; i < 8; i++) {
            V[0][i] -= xo[i];
            V[1][i] -= yo[i];
            V[2][i] = fmaf(-xo[i], xo[i], V[2][i]);
            V[3][i] = fmaf(-yo[i], yo[i], V[3][i]);
            V[4][i] = fmaf(-xo[i], yo[i], V[4][i]);
        }
    }

    // single-wave block: shuffle reduction, one double atomic per block
    // into this image's slot (spreads atomic traffic over 96 cachelines)
#pragma unroll
    for (int off = 32; off > 0; off >>= 1)
        sacc += __shfl_down(sacc, off);
    if (lane == 0) atomicAdd(&acc[img], (double)sacc);
}

__global__ void ssim_finalize(const double* __restrict__ acc, float* __restrict__ out)
{
    double s = 0.0;
    for (int i = 0; i < NIMG; i++) s += acc[i];
    out[0] = (float)(s / NPIX);
}

extern "C" void kernel_launch(void* const* d_in, const int* in_sizes, int n_in,
                              void* d_out, int out_size, void* d_ws, size_t ws_size,
                              hipStream_t stream)
{
    const float* X = (const float*)d_in[0];   // input_tensor (32,3,512,512) fp32
    const float* Y = (const float*)d_in[1];   // target       (32,3,512,512) fp32
    float* out = (float*)d_out;               // scalar fp32
    double* acc = (double*)d_ws;

    hipMemsetAsync(d_ws, 0, NIMG * sizeof(double), stream);
    ssim_main<<<dim3(NSTRIP, NIMG), 64, 0, stream>>>(X, Y, acc);
    ssim_finalize<<<1, 1, 0, stream>>>(acc, out);
}

// Round 7
// 258.407 us; speedup vs baseline: 2.1035x; 2.1035x over previous
//
#include <hip/hip_runtime.h>

// SSIM (win=7, valid) fused single-pass kernel for (32,3,512,512) fp32 inputs.
// 96 images of 512x512 -> mean over 96x506x506 S map.
//
// R7: byte-count attack. R1-R6 invariant: ~4-4.5 TB/s total vector-load
// traffic regardless of structure (occupancy 17-67%, VALU<=43%) -> the
// memory path is the ceiling; minimize bytes through it. Previously each row
// was read ~2.3x from global (bottom-add + top-subtract 7 iters later, L1
// long evicted). Now: 8-row x/y ring buffer in LDS (32KB/block); a row's
// x,y are ds_written when added and ds_read back for the subtract. Same
// lane, same address, wave-in-order DS -> NO barriers. Global traffic:
// exactly one read per input row: 52 rows per 46-output strip = 220 MB.
// R4 wave-private compute kept: 8 cols/lane, shuffle halo, register H-slide,
// folded constants, v_rcp. NOTE (R6 lesson): no min-waves launch bound —
// capping VGPRs below the working set spills to scratch catastrophically.

namespace {
constexpr int W      = 512;
constexpr int HH     = 512;
constexpr int NIMG   = 96;
constexpr int OW     = 506;
constexpr int RSTRIP = 46;   // 11 * 46 = 506 output rows exactly
constexpr int NSTRIP = 11;
// S = (2 ux uy + C1)(2 vxy + C2) / ((ux^2+uy^2+C1)(vx+vy+C2)); with U = 49*u
// window sums, every term carries 1/2401 which cancels in the ratio:
constexpr float D1      = 0.2401f;                  // C1 * 49^2
constexpr float D2      = 2.1609f;                  // C2 * 49^2
constexpr float COVN    = 49.0f / 48.0f;            // NP/(NP-1)
constexpr float COV2    = 2.0f * COVN;
constexpr float K49COV  = 49.0f * COVN;
constexpr float K49COV2 = 2.0f * 49.0f * COVN;
constexpr double NPIX   = 96.0 * 506.0 * 506.0;     // 24,579,456
}

__global__ __launch_bounds__(64) void ssim_main(const float* __restrict__ X,
                                                const float* __restrict__ Y,
                                                double* __restrict__ acc)
{
    // 8-slot ring of (x,y) rows: slot s = x[512] floats then y[512] floats.
    __shared__ float ring[8 * 1024];

    const int lane = threadIdx.x;              // 0..63 (one wave per block)
    const int img  = blockIdx.y;
    const int r0   = blockIdx.x * RSTRIP;      // first output row of strip
    const int c0   = lane * 8;                 // this lane's first column

    const float* xb = X + (size_t)img * (W * HH) + c0;
    const float* yb = Y + (size_t)img * (W * HH) + c0;

    float* ringx = &ring[c0];                  // this lane's x slice, slot 0
    float* ringy = &ring[512 + c0];            // this lane's y slice, slot 0

    // vertical running sums over the 7-row window, per own column 0..7:
    // V[0]=sum x, V[1]=sum y, V[2]=sum x^2, V[3]=sum y^2, V[4]=sum x*y
    float V[5][8];
#pragma unroll
    for (int q = 0; q < 5; q++)
#pragma unroll
        for (int i = 0; i < 8; i++) V[q][i] = 0.0f;

    float xr[8], yr[8];

    auto gload_row = [&](int r, float (&dx)[8], float (&dy)[8]) {
        const float* px = xb + (size_t)r * W;
        const float* py = yb + (size_t)r * W;
        float4 a = *(const float4*)px;
        float4 b = *(const float4*)(px + 4);
        dx[0] = a.x; dx[1] = a.y; dx[2] = a.z; dx[3] = a.w;
        dx[4] = b.x; dx[5] = b.y; dx[6] = b.z; dx[7] = b.w;
        float4 e = *(const float4*)py;
        float4 f = *(const float4*)(py + 4);
        dy[0] = e.x; dy[1] = e.y; dy[2] = e.z; dy[3] = e.w;
        dy[4] = f.x; dy[5] = f.y; dy[6] = f.z; dy[7] = f.w;
    };
    auto ring_write = [&](int slot, const float (&dx)[8], const float (&dy)[8]) {
        float* px = ringx + slot * 1024;
        float* py = ringy + slot * 1024;
        *(float4*)(px)     = make_float4(dx[0], dx[1], dx[2], dx[3]);
        *(float4*)(px + 4) = make_float4(dx[4], dx[5], dx[6], dx[7]);
        *(float4*)(py)     = make_float4(dy[0], dy[1], dy[2], dy[3]);
        *(float4*)(py + 4) = make_float4(dy[4], dy[5], dy[6], dy[7]);
    };
    auto ring_read = [&](int slot, float (&dx)[8], float (&dy)[8]) {
        const float* px = ringx + slot * 1024;
        const float* py = ringy + slot * 1024;
        float4 a = *(const float4*)px;
        float4 b = *(const float4*)(px + 4);
        dx[0] = a.x; dx[1] = a.y; dx[2] = a.z; dx[3] = a.w;
        dx[4] = b.x; dx[5] = b.y; dx[6] = b.z; dx[7] = b.w;
        float4 e = *(const float4*)py;
        float4 f = *(const float4*)(py + 4);
        dy[0] = e.x; dy[1] = e.y; dy[2] = e.z; dy[3] = e.w;
        dy[4] = f.x; dy[5] = f.y; dy[6] = f.z; dy[7] = f.w;
    };
    auto vadd = [&](const float (&xs)[8], const float (&ys)[8]) {
#pragma unroll
        for (int i = 0; i < 8; i++) {
            V[0][i] += xs[i];
            V[1][i] += ys[i];
            V[2][i] = fmaf(xs[i], xs[i], V[2][i]);
            V[3][i] = fmaf(ys[i], ys[i], V[3][i]);
            V[4][i] = fmaf(xs[i], ys[i], V[4][i]);
        }
    };

    // warm-up: rows r0 .. r0+5 -> V and ring slots 0..5
#pragma unroll
    for (int k = 0; k < 6; k++) {
        gload_row(r0 + k, xr, yr);
        vadd(xr, yr);
        ring_write(k, xr, yr);
    }
    // first bottom row (r0+6) into regs; written to ring at its add (iter 0)
    gload_row(r0 + 6, xr, yr);

    float sacc = 0.0f;

#pragma unroll 2
    for (int j = 0; j < RSTRIP; j++) {
        // add bottom row (r0+j+6), already in xr/yr; stage it to ring slot (j+6)&7
        vadd(xr, yr);
        ring_write((j + 6) & 7, xr, yr);

        // global load of next bottom row (r0+j+7) — the ONLY global read.
        // Clamped on last iter (dead value).
        int rn = r0 + j + 7; if (rn > HH - 1) rn = HH - 1;
        float xn[8], yn[8];
        gload_row(rn, xn, yn);

        // top row (r0+j) for the subtract comes from the ring, not global.
        float xo[8], yo[8];
        ring_read(j & 7, xo, yo);

        // halo: V cols 8..13 = lane+1's cols 0..5 (lane 63's garbage feeds
        // only masked pixels)
        float Vh[5][6];
#pragma unroll
        for (int q = 0; q < 5; q++)
#pragma unroll
            for (int i = 0; i < 6; i++) Vh[q][i] = __shfl_down(V[q][i], 1);

        // horizontal window init (cols 0..6), then slide across 8 outputs
        float H[5];
#pragma unroll
        for (int q = 0; q < 5; q++)
            H[q] = ((V[q][0] + V[q][1]) + (V[q][2] + V[q][3])) +
                   ((V[q][4] + V[q][5]) + V[q][6]);

#pragma unroll
        for (int i = 0; i < 8; i++) {
            float U0 = H[0], U1 = H[1], U2 = H[2], U3 = H[3], U4 = H[4];
            float A    = U0 * U1;
            float q01  = fmaf(U0, U0, U1 * U1);
            float num1 = fmaf(2.0f, A, D1);
            float den1 = q01 + D1;
            float num2 = fmaf(K49COV2, U4, fmaf(-COV2, A, D2));
            float s23  = U2 + U3;
            float den2 = fmaf(K49COV, s23, fmaf(-COVN, q01, D2));
            float S = (num1 * num2) * __builtin_amdgcn_rcpf(den1 * den2);
            sacc += (c0 + i < OW) ? S : 0.0f;
            if (i < 7) {
                // slide window i..i+6 -> i+1..i+7: add col i+7, drop col i
#pragma unroll
                for (int q = 0; q < 5; q++) {
                    float addv = (i == 0) ? V[q][7] : Vh[q][i - 1];
                    H[q] += addv - V[q][i];
                }
            }
        }

        // subtract top row (r0+j)
#pragma unroll
        for (int i = 0; i < 8; i++) {
            V[0][i] -= xo[i];
            V[1][i] -= yo[i];
            V[2][i] = fmaf(-xo[i], xo[i], V[2][i]);
            V[3][i] = fmaf(-yo[i], yo[i], V[3][i]);
            V[4][i] = fmaf(-xo[i], yo[i], V[4][i]);
        }

        // rotate prefetched bottom row into place
#pragma unroll
        for (int i = 0; i < 8; i++) { xr[i] = xn[i]; yr[i] = yn[i]; }
    }

    // single-wave block: shuffle reduction, one double atomic per image slot
#pragma unroll
    for (int off = 32; off > 0; off >>= 1)
        sacc += __shfl_down(sacc, off);
    if (lane == 0) atomicAdd(&acc[img], (double)sacc);
}

__global__ void ssim_finalize(const double* __restrict__ acc, float* __restrict__ out)
{
    double s = 0.0;
    for (int i = 0; i < NIMG; i++) s += acc[i];
    out[0] = (float)(s / NPIX);
}

extern "C" void kernel_launch(void* const* d_in, const int* in_sizes, int n_in,
                              void* d_out, int out_size, void* d_ws, size_t ws_size,
                              hipStream_t stream)
{
    const float* X = (const float*)d_in[0];   // input_tensor (32,3,512,512) fp32
    const float* Y = (const float*)d_in[1];   // target       (32,3,512,512) fp32
    float* out = (float*)d_out;               // scalar fp32
    double* acc = (double*)d_ws;

    hipMemsetAsync(d_ws, 0, NIMG * sizeof(double), stream);
    ssim_main<<<dim3(NSTRIP, NIMG), 64, 0, stream>>>(X, Y, acc);
    ssim_finalize<<<1, 1, 0, stream>>>(acc, out);
}